// Round 12
// baseline (257.177 us; speedup 1.0000x reference)
//
#include <hip/hip_runtime.h>
#include <hip/hip_cooperative_groups.h>
#include <math.h>

namespace cg = cooperative_groups;

#define N_NODES 50000
#define N_EDGES 800000
#define N_GRAPHS 128
#define DIM0 256
#define DIM1 128
#define DIM2 32

#define NBUCK 196      // buckets of 256 rows
#define NEB 98         // edge blocks (8192 edges each)

using f32x4 = __attribute__((ext_vector_type(4))) float;
using s16x8 = __attribute__((ext_vector_type(8))) short;

// ---- bf16 pack/unpack helpers (RNE) ----
__device__ inline unsigned bf16pack(float a, float b) {
    unsigned ua = __float_as_uint(a), ub = __float_as_uint(b);
    ua = (ua + 0x7fffu + ((ua >> 16) & 1u)) >> 16;
    ub = (ub + 0x7fffu + ((ub >> 16) & 1u)) >> 16;
    return ua | (ub << 16);
}
__device__ inline float2 bf16x2(unsigned p) {
    return make_float2(__uint_as_float(p << 16), __uint_as_float(p & 0xffff0000u));
}

// packed-position -> true feature index for the h1u/a1 bf16 layout:
// uint j holds features (32*(j>>4)+(j&15), +16); bf16 position p=2j+b
__device__ inline int featOf(int p) {
    return 32 * (p >> 5) + ((p >> 1) & 15) + 16 * (p & 1);
}

// ================ cooperative build: hist/prep -> place -> build ================
// 196 blocks x 256. Phase A: blocks 0..97 histogram, 98..113 W1/W2 swizzle + gstart,
// 114 zeroes pooled. Phase B: blocks 0..97 place edges bucket-major. Phase C: all
// 196 blocks sort their bucket into dense ushort CSR + offs/cnt.
__global__ __launch_bounds__(256) void k_build_coop(const float* __restrict__ W1, uint* __restrict__ W1b,
                                                    const float* __restrict__ W2, uint* __restrict__ W2b,
                                                    const int* __restrict__ batch, int* gstart,
                                                    const int* __restrict__ row, const int* __restrict__ col,
                                                    int* __restrict__ hist, uint* __restrict__ bb,
                                                    int* __restrict__ bbase, int* __restrict__ btot,
                                                    int* __restrict__ offs, int* __restrict__ cnt,
                                                    ushort* __restrict__ csr, float* __restrict__ pooled) {
    __shared__ int h[NBUCK];
    __shared__ int cur[NBUCK];
    __shared__ int tot[NBUCK];
    __shared__ int sc[256];
    __shared__ int c256[256];
    __shared__ int cur256[256];
    __shared__ int wsum[4];
    cg::grid_group grid = cg::this_grid();
    int b = blockIdx.x, t = threadIdx.x;

    // ---------- Phase A ----------
    if (b < NEB) {
        if (t < NBUCK) h[t] = 0;
        __syncthreads();
#pragma unroll
        for (int i = 0; i < 8; ++i) {
            int idx = b * 2048 + i * 256 + t;
            if (idx < N_EDGES / 4) {
                int4 r4 = ((const int4*)row)[idx];
                atomicAdd(&h[r4.x >> 8], 1);
                atomicAdd(&h[r4.y >> 8], 1);
                atomicAdd(&h[r4.z >> 8], 1);
                atomicAdd(&h[r4.w >> 8], 1);
            }
        }
        __syncthreads();
        if (t < NBUCK) hist[b * NBUCK + t] = h[t];   // block-major
    } else if (b < NEB + 16) {
        int g = (b - NEB) * 256 + t;   // 0..4095
        {
            int s = g >> 9, tt = (g >> 6) & 7, q = (g >> 4) & 3, n = g & 15;
            int k0 = s * 32 + q * 8;
            int colw = tt * 16 + n;
            uint4 o;
            o.x = bf16pack(W1[(size_t)(k0 + 0) * DIM1 + colw], W1[(size_t)(k0 + 1) * DIM1 + colw]);
            o.y = bf16pack(W1[(size_t)(k0 + 2) * DIM1 + colw], W1[(size_t)(k0 + 3) * DIM1 + colw]);
            o.z = bf16pack(W1[(size_t)(k0 + 4) * DIM1 + colw], W1[(size_t)(k0 + 5) * DIM1 + colw]);
            o.w = bf16pack(W1[(size_t)(k0 + 6) * DIM1 + colw], W1[(size_t)(k0 + 7) * DIM1 + colw]);
            ((uint4*)W1b)[g] = o;
        }
        if (g < 512) {   // W2 B-fragments (rows permuted per featOf)
            int s = g >> 7, tt = (g >> 6) & 1, l = g & 63;
            int n = tt * 16 + (l & 15);
            int kb = s * 32 + (l >> 4) * 8;
            uint4 o;
            o.x = bf16pack(W2[(size_t)featOf(kb + 0) * DIM2 + n], W2[(size_t)featOf(kb + 1) * DIM2 + n]);
            o.y = bf16pack(W2[(size_t)featOf(kb + 2) * DIM2 + n], W2[(size_t)featOf(kb + 3) * DIM2 + n]);
            o.z = bf16pack(W2[(size_t)featOf(kb + 4) * DIM2 + n], W2[(size_t)featOf(kb + 5) * DIM2 + n]);
            o.w = bf16pack(W2[(size_t)featOf(kb + 6) * DIM2 + n], W2[(size_t)featOf(kb + 7) * DIM2 + n]);
            ((uint4*)W2b)[g] = o;
        }
        if (g <= N_GRAPHS) {
            int lo = 0, hi = N_NODES;
            while (lo < hi) { int mid = (lo + hi) >> 1; if (batch[mid] < g) lo = mid + 1; else hi = mid; }
            gstart[g] = lo;
        }
    } else if (b == NEB + 16) {
        for (int i = t; i < N_GRAPHS * DIM2; i += 256) pooled[i] = 0.f;
    }

    grid.sync();

    // ---------- Phase B: place ----------
    if (b < NEB) {
        int pre = 0, to = 0;
        for (int b2 = 0; b2 < NEB; ++b2) {
            int v = (t < NBUCK) ? hist[b2 * NBUCK + t] : 0;
            to += v;
            if (b2 < b) pre += v;
        }
        if (t < NBUCK) tot[t] = to;
        sc[t] = (t < NBUCK) ? to : 0;
        __syncthreads();
        for (int off = 1; off < 256; off <<= 1) {
            int x = (t >= off) ? sc[t - off] : 0;
            __syncthreads();
            sc[t] += x;
            __syncthreads();
        }
        if (t < NBUCK) {
            int base = sc[t] - tot[t];          // exclusive bucket base
            cur[t] = base + pre;
            if (b == 0) { bbase[t] = base; btot[t] = tot[t]; }
        }
        __syncthreads();
#pragma unroll
        for (int i = 0; i < 8; ++i) {
            int idx = b * 2048 + i * 256 + t;
            if (idx < N_EDGES / 4) {
                int4 r4 = ((const int4*)row)[idx];
                int4 c4 = ((const int4*)col)[idx];
                int rs[4] = {r4.x, r4.y, r4.z, r4.w};
                int cs[4] = {c4.x, c4.y, c4.z, c4.w};
#pragma unroll
                for (int j = 0; j < 4; ++j) {
                    int pos = atomicAdd(&cur[rs[j] >> 8], 1);
                    bb[pos] = ((uint)(rs[j] & 255) << 16) | (uint)cs[j];
                }
            }
        }
    }

    grid.sync();

    // ---------- Phase C: build (all 196 blocks) ----------
    {
        int start = bbase[b];
        int n = btot[b];
        c256[t] = 0;
        __syncthreads();
        for (int i = t; i < n; i += 256) atomicAdd(&c256[bb[start + i] >> 16], 1);
        __syncthreads();
        int w = t >> 6, l = t & 63;
        int v = c256[t];
        int incl = v;
#pragma unroll
        for (int off = 1; off < 64; off <<= 1) {
            int x = __shfl_up(incl, off, 64);
            if (l >= off) incl += x;
        }
        if (l == 63) wsum[w] = incl;
        __syncthreads();
        int woff = 0;
        for (int i = 0; i < w; ++i) woff += wsum[i];
        int excl = incl - v + woff;
        cur256[t] = excl;
        int r = b * 256 + t;
        if (r < N_NODES) { offs[r] = start + excl; cnt[r] = v; }
        __syncthreads();
        for (int i = t; i < n; i += 256) {
            uint e = bb[start + i];
            int pos = atomicAdd(&cur256[e >> 16], 1);
            csr[start + pos] = (ushort)(e & 0xFFFFu);
        }
    }
}

// ---------------- GEMM1 (MFMA bf16): h1'[50000,128] = dinv * (X @ W1) ----------------
// h1u feature permutation: uint j = u*16+c holds features (32u+c, 32u+c+16).
#define G1_BM 128
#define AS_LD 20  // uints per row (16 data + 4 pad = 80 B)
__global__ __launch_bounds__(256) void k_gemm1(const float* __restrict__ X, const uint* __restrict__ W1b,
                                               const int* __restrict__ cnt, unsigned* __restrict__ h1u) {
    __shared__ uint w1s[16384];        // 64 KB: full W1 in B-frag order
    __shared__ uint As[G1_BM * AS_LD]; // 10 KB: A tile bf16, one K-step
    int t = threadIdx.x;
    int w = t >> 6, lane = t & 63, q = lane >> 4, m16 = lane & 15;
    int rowBase = blockIdx.x * G1_BM;

    {
        const uint4* src = (const uint4*)W1b;
        uint4* dst = (uint4*)w1s;
#pragma unroll
        for (int i = 0; i < 16; ++i) dst[i * 256 + t] = src[i * 256 + t];
    }

    f32x4 acc[2][8];
#pragma unroll
    for (int i = 0; i < 2; ++i)
#pragma unroll
        for (int j = 0; j < 8; ++j) acc[i][j] = (f32x4){0.f, 0.f, 0.f, 0.f};

    int ar = t >> 1, ah = t & 1;
    for (int s = 0; s < 8; ++s) {
        float4 f0 = {0,0,0,0}, f1 = {0,0,0,0}, f2 = {0,0,0,0}, f3 = {0,0,0,0};
        int grow = rowBase + ar;
        if (grow < N_NODES) {
            const float* src = X + (size_t)grow * DIM0 + s * 32 + ah * 16;
            f0 = *(const float4*)(src + 0);
            f1 = *(const float4*)(src + 4);
            f2 = *(const float4*)(src + 8);
            f3 = *(const float4*)(src + 12);
        }
        uint4 p0, p1;
        p0.x = bf16pack(f0.x, f0.y); p0.y = bf16pack(f0.z, f0.w);
        p0.z = bf16pack(f1.x, f1.y); p0.w = bf16pack(f1.z, f1.w);
        p1.x = bf16pack(f2.x, f2.y); p1.y = bf16pack(f2.z, f2.w);
        p1.z = bf16pack(f3.x, f3.y); p1.w = bf16pack(f3.z, f3.w);
        __syncthreads();
        *(uint4*)&As[ar * AS_LD + ah * 8 + 0] = p0;
        *(uint4*)&As[ar * AS_LD + ah * 8 + 4] = p1;
        __syncthreads();

        s16x8 af[2];
#pragma unroll
        for (int rt = 0; rt < 2; ++rt) {
            int arow = w * 32 + rt * 16 + m16;
            af[rt] = *(s16x8*)&As[arow * AS_LD + q * 4];
        }
#pragma unroll
        for (int tt = 0; tt < 8; ++tt) {
            s16x8 bf = *(s16x8*)&w1s[((s * 8 + tt) * 64 + lane) * 4];
            acc[0][tt] = __builtin_amdgcn_mfma_f32_16x16x32_bf16(af[0], bf, acc[0][tt], 0, 0, 0);
            acc[1][tt] = __builtin_amdgcn_mfma_f32_16x16x32_bf16(af[1], bf, acc[1][tt], 0, 0, 0);
        }
    }

#pragma unroll
    for (int rt = 0; rt < 2; ++rt) {
#pragma unroll
        for (int reg = 0; reg < 4; ++reg) {
            int row = rowBase + w * 32 + rt * 16 + q * 4 + reg;
            if (row < N_NODES) {
                float dv = rsqrtf((float)(cnt[row] + 1));
                unsigned* hr = h1u + (size_t)row * 64;
#pragma unroll
                for (int u = 0; u < 4; ++u)
                    hr[u * 16 + m16] = bf16pack(acc[rt][2 * u][reg] * dv, acc[rt][2 * u + 1][reg] * dv);
            }
        }
    }
}

// ---------------- agg1+gemm2 fused: block = 16 nodes ----------------
#define A1_LD 68   // uints per tile row (64 + 4 pad)
__global__ __launch_bounds__(256) void k_agg1g2(const unsigned* __restrict__ h1u, const int* __restrict__ cnt,
                                                const int* __restrict__ offs, const ushort* __restrict__ csr,
                                                const float* __restrict__ b1, const uint* __restrict__ W2b,
                                                unsigned* __restrict__ h2u) {
    __shared__ uint a1tile[16 * A1_LD];
    __shared__ float sdi[16];
    int t = threadIdx.x;
    int wv = t >> 6, lane = t & 63;
    int nb16 = blockIdx.x * 16;

#pragma unroll
    for (int i = 0; i < 4; ++i) {
        int m = wv * 4 + i;
        int node = nb16 + m;
        float2 acc = bf16x2(h1u[(size_t)node * 64 + lane]);  // self (already dinv-scaled)
        int n = cnt[node];
        const ushort* cp = csr + offs[node];
        int ec = 0;
        if (lane < n) ec = cp[lane];
        int j = 0;
        for (; j + 8 <= n; j += 8) {
            int c0 = __shfl(ec, j),     c1 = __shfl(ec, j + 1), c2 = __shfl(ec, j + 2), c3 = __shfl(ec, j + 3);
            int c4 = __shfl(ec, j + 4), c5 = __shfl(ec, j + 5), c6 = __shfl(ec, j + 6), c7 = __shfl(ec, j + 7);
            unsigned p0 = h1u[(size_t)c0 * 64 + lane];
            unsigned p1 = h1u[(size_t)c1 * 64 + lane];
            unsigned p2 = h1u[(size_t)c2 * 64 + lane];
            unsigned p3 = h1u[(size_t)c3 * 64 + lane];
            unsigned p4 = h1u[(size_t)c4 * 64 + lane];
            unsigned p5 = h1u[(size_t)c5 * 64 + lane];
            unsigned p6 = h1u[(size_t)c6 * 64 + lane];
            unsigned p7 = h1u[(size_t)c7 * 64 + lane];
            float2 v0 = bf16x2(p0), v1 = bf16x2(p1), v2 = bf16x2(p2), v3 = bf16x2(p3);
            float2 v4 = bf16x2(p4), v5 = bf16x2(p5), v6 = bf16x2(p6), v7 = bf16x2(p7);
            acc.x += (v0.x + v1.x) + (v2.x + v3.x) + (v4.x + v5.x) + (v6.x + v7.x);
            acc.y += (v0.y + v1.y) + (v2.y + v3.y) + (v4.y + v5.y) + (v6.y + v7.y);
        }
        for (; j + 4 <= n; j += 4) {
            int c0 = __shfl(ec, j), c1 = __shfl(ec, j + 1), c2 = __shfl(ec, j + 2), c3 = __shfl(ec, j + 3);
            unsigned p0 = h1u[(size_t)c0 * 64 + lane];
            unsigned p1 = h1u[(size_t)c1 * 64 + lane];
            unsigned p2 = h1u[(size_t)c2 * 64 + lane];
            unsigned p3 = h1u[(size_t)c3 * 64 + lane];
            float2 v0 = bf16x2(p0), v1 = bf16x2(p1), v2 = bf16x2(p2), v3 = bf16x2(p3);
            acc.x += (v0.x + v1.x) + (v2.x + v3.x);
            acc.y += (v0.y + v1.y) + (v2.y + v3.y);
        }
        for (; j < n; ++j) {
            int c = __shfl(ec, j);
            float2 v = bf16x2(h1u[(size_t)c * 64 + lane]);
            acc.x += v.x; acc.y += v.y;
        }
        float di = rsqrtf((float)(n + 1));
        if (lane == 0) sdi[m] = di;
        int f0 = (lane >> 4) * 32 + (lane & 15);
        acc.x = fmaxf(acc.x * di + b1[f0], 0.f);
        acc.y = fmaxf(acc.y * di + b1[f0 + 16], 0.f);
        a1tile[m * A1_LD + lane] = bf16pack(acc.x, acc.y);
    }
    __syncthreads();

    if (wv == 0) {
        int q = lane >> 4, m16 = lane & 15;
        f32x4 accA = (f32x4){0.f, 0.f, 0.f, 0.f};
        f32x4 accB = (f32x4){0.f, 0.f, 0.f, 0.f};
#pragma unroll
        for (int s = 0; s < 4; ++s) {
            s16x8 af = *(s16x8*)&a1tile[m16 * A1_LD + s * 16 + q * 4];
            s16x8 bf0 = *(const s16x8*)(W2b + (size_t)((s * 2 + 0) * 64 + lane) * 4);
            s16x8 bf1 = *(const s16x8*)(W2b + (size_t)((s * 2 + 1) * 64 + lane) * 4);
            accA = __builtin_amdgcn_mfma_f32_16x16x32_bf16(af, bf0, accA, 0, 0, 0);
            accB = __builtin_amdgcn_mfma_f32_16x16x32_bf16(af, bf1, accB, 0, 0, 0);
        }
#pragma unroll
        for (int r = 0; r < 4; ++r) {
            int node = nb16 + q * 4 + r;
            float dv = sdi[q * 4 + r];
            // h2u position m16 holds output features (m16, m16+16)
            h2u[(size_t)node * 16 + m16] = bf16pack(accA[r] * dv, accB[r] * dv);
        }
    }
}

// ---------------- agg2 + per-graph partial pool: block = 16 nodes ----------------
// lane l of a 16-lane group computes features (l, l+16) of its node's aggregation
// (no b2 here; it commutes with the mean and is added in k_final). Block segment-
// reduces by graph (batch sorted -> ~1 segment/block) and emits ~32 atomicAdds
// per segment into pooled[g*32 + f] (natural feature order).
__global__ __launch_bounds__(256) void k_agg2pool(const unsigned* __restrict__ h2u, const int* __restrict__ cnt,
                                                  const int* __restrict__ offs, const ushort* __restrict__ csr,
                                                  const int* __restrict__ batch, float* __restrict__ pooled) {
    __shared__ float2 red[16][16];
    int t = threadIdx.x;
    int nb16 = blockIdx.x * 16;
    int node = nb16 + (t >> 4);
    int l = t & 15;
    float2 acc = bf16x2(h2u[(size_t)node * 16 + l]);  // self term
    int n = cnt[node];
    const ushort* cp = csr + offs[node];
    for (int base = 0; base < n; base += 16) {
        int m = min(16, n - base);
        int ec = 0;
        if (l < m) ec = cp[base + l];
        int j = 0;
        for (; j + 4 <= m; j += 4) {
            int c0 = __shfl(ec, j, 16), c1 = __shfl(ec, j + 1, 16);
            int c2 = __shfl(ec, j + 2, 16), c3 = __shfl(ec, j + 3, 16);
            unsigned p0 = h2u[(size_t)c0 * 16 + l];
            unsigned p1 = h2u[(size_t)c1 * 16 + l];
            unsigned p2 = h2u[(size_t)c2 * 16 + l];
            unsigned p3 = h2u[(size_t)c3 * 16 + l];
            float2 v0 = bf16x2(p0), v1 = bf16x2(p1), v2 = bf16x2(p2), v3 = bf16x2(p3);
            acc.x += v0.x + v1.x + v2.x + v3.x;
            acc.y += v0.y + v1.y + v2.y + v3.y;
        }
        for (; j < m; ++j) {
            int c = __shfl(ec, j, 16);
            float2 v = bf16x2(h2u[(size_t)c * 16 + l]);
            acc.x += v.x; acc.y += v.y;
        }
    }
    float di = rsqrtf((float)(n + 1));
    red[t >> 4][l] = make_float2(acc.x * di, acc.y * di);
    __syncthreads();
    if (t < 16) {
        float2 run = make_float2(0.f, 0.f);
        int gprev = batch[nb16];
        for (int m = 0; m < 16; ++m) {
            int g = batch[nb16 + m];
            if (g != gprev) {
                atomicAdd(&pooled[gprev * DIM2 + t], run.x);
                atomicAdd(&pooled[gprev * DIM2 + t + 16], run.y);
                run = make_float2(0.f, 0.f);
                gprev = g;
            }
            float2 v = red[m][t];
            run.x += v.x; run.y += v.y;
        }
        atomicAdd(&pooled[gprev * DIM2 + t], run.x);
        atomicAdd(&pooled[gprev * DIM2 + t + 16], run.y);
    }
}

// ---------------- final: mean + bias + log_softmax (1 wave / graph) ----------------
__global__ __launch_bounds__(64) void k_final(const float* __restrict__ pooled, const int* __restrict__ gstart,
                                              const float* __restrict__ b2, float* __restrict__ out) {
    int g = blockIdx.x;
    int lane = threadIdx.x;
    float cntf = fmaxf((float)(gstart[g + 1] - gstart[g]), 1.0f);
    float val = 0.f, v = -INFINITY;
    if (lane < DIM2) {
        val = pooled[g * DIM2 + lane] / cntf + b2[lane];
        v = val;
    }
#pragma unroll
    for (int m = 16; m >= 1; m >>= 1) v = fmaxf(v, __shfl_xor(v, m, 32));
    float ex = (lane < DIM2) ? expf(val - v) : 0.f;
#pragma unroll
    for (int m = 16; m >= 1; m >>= 1) ex += __shfl_xor(ex, m, 32);
    if (lane < DIM2) out[g * DIM2 + lane] = val - v - logf(ex);
}

extern "C" void kernel_launch(void* const* d_in, const int* in_sizes, int n_in,
                              void* d_out, int out_size, void* d_ws, size_t ws_size,
                              hipStream_t stream) {
    const float* x     = (const float*)d_in[0];
    const int*   eidx  = (const int*)d_in[1];
    const int*   batch = (const int*)d_in[2];
    const float* W1    = (const float*)d_in[3];
    const float* b1    = (const float*)d_in[4];
    const float* W2    = (const float*)d_in[5];
    const float* b2    = (const float*)d_in[6];
    const int* row = eidx;
    const int* col = eidx + N_EDGES;
    float* out = (float*)d_out;

    // workspace layout (16B aligned chunks)
    char* p = (char*)d_ws;
    int*    cnt    = (int*)p;    p += (size_t)N_NODES * 4;
    int*    offs   = (int*)p;    p += (size_t)N_NODES * 4 + 16;
    int*    gstart = (int*)p;    p += 768;          // 129 ints, padded
    uint*   W1b    = (uint*)p;   p += 4096 * 16;    // 64 KB swizzled bf16 W1
    uint*   W2b    = (uint*)p;   p += 512 * 16;     // 8 KB W2 B-fragments
    int*    hist   = (int*)p;    p += (size_t)NEB * NBUCK * 4 + 32;  // 77 KB, block-major
    int*    bbase  = (int*)p;    p += 1024;
    int*    btot   = (int*)p;    p += 1024;
    float*  pooled = (float*)p;  p += (size_t)N_GRAPHS * DIM2 * 4;   // 16 KB
    uint*   bb     = (uint*)p;   p += (size_t)N_EDGES * 4;           // 3.2 MB staging
    ushort* csr    = (ushort*)p; p += (size_t)N_EDGES * 2;           // 1.6 MB dense CSR
    unsigned* h1u  = (unsigned*)p; p += (size_t)N_NODES * 64 * 4;    // 12.8 MB
    unsigned* h2u  = (unsigned*)p; p += (size_t)N_NODES * 16 * 4;    // 3.2 MB

    {
        void* args[] = { (void*)&W1, (void*)&W1b, (void*)&W2, (void*)&W2b,
                         (void*)&batch, (void*)&gstart, (void*)&row, (void*)&col,
                         (void*)&hist, (void*)&bb, (void*)&bbase, (void*)&btot,
                         (void*)&offs, (void*)&cnt, (void*)&csr, (void*)&pooled };
        hipLaunchCooperativeKernel((const void*)k_build_coop, dim3(NBUCK), dim3(256),
                                   args, 0, stream);
    }

    k_gemm1<<<(N_NODES + G1_BM - 1) / G1_BM, 256, 0, stream>>>(x, W1b, cnt, h1u);
    k_agg1g2<<<N_NODES / 16, 256, 0, stream>>>(h1u, cnt, offs, csr, b1, W2b, h2u);
    k_agg2pool<<<N_NODES / 16, 256, 0, stream>>>(h2u, cnt, offs, csr, batch, pooled);
    k_final<<<N_GRAPHS, 64, 0, stream>>>(pooled, gstart, b2, out);
}

// Round 13
// 190.208 us; speedup vs baseline: 1.3521x; 1.3521x over previous
//
#include <hip/hip_runtime.h>
#include <math.h>

#define N_NODES 50000
#define N_EDGES 800000
#define N_GRAPHS 128
#define DIM0 256
#define DIM1 128
#define DIM2 32

#define NBUCK 196      // buckets of 256 rows
#define NEB 98         // edge blocks (8192 edges each)

using f32x4 = __attribute__((ext_vector_type(4))) float;
using s16x8 = __attribute__((ext_vector_type(8))) short;

// ---- bf16 pack/unpack helpers (RNE) ----
__device__ inline unsigned bf16pack(float a, float b) {
    unsigned ua = __float_as_uint(a), ub = __float_as_uint(b);
    ua = (ua + 0x7fffu + ((ua >> 16) & 1u)) >> 16;
    ub = (ub + 0x7fffu + ((ub >> 16) & 1u)) >> 16;
    return ua | (ub << 16);
}
__device__ inline float2 bf16x2(unsigned p) {
    return make_float2(__uint_as_float(p << 16), __uint_as_float(p & 0xffff0000u));
}

// packed-position -> true feature index for the h1u/a1 bf16 layout:
// uint j holds features (32*(j>>4)+(j&15), +16); bf16 position p=2j+b
__device__ inline int featOf(int p) {
    return 32 * (p >> 5) + ((p >> 1) & 15) + 16 * (p & 1);
}

// ---------------- hist: per-block LDS histogram over 196 row-buckets ----------------
__global__ __launch_bounds__(256) void k_hist(const int* __restrict__ row, int* __restrict__ hist) {
    __shared__ int h[NBUCK];
    int b = blockIdx.x, t = threadIdx.x;
    if (t < NBUCK) h[t] = 0;
    __syncthreads();
#pragma unroll
    for (int i = 0; i < 8; ++i) {
        int idx = b * 2048 + i * 256 + t;
        if (idx < N_EDGES / 4) {
            int4 r4 = ((const int4*)row)[idx];
            atomicAdd(&h[r4.x >> 8], 1);
            atomicAdd(&h[r4.y >> 8], 1);
            atomicAdd(&h[r4.z >> 8], 1);
            atomicAdd(&h[r4.w >> 8], 1);
        }
    }
    __syncthreads();
    if (t < NBUCK) hist[b * NBUCK + t] = h[t];   // block-major
}

// ---------------- place (blocks 0..97) + independent prep (blocks 98..114) ----------------
// Prep blocks do W1/W2 swizzle, gstart binary search, pooled zeroing — none of it
// depends on hist, so it hides behind place's work in the same launch.
__global__ __launch_bounds__(256) void k_place(const int* __restrict__ row, const int* __restrict__ col,
                                               const int* __restrict__ hist, uint* __restrict__ bb,
                                               int* __restrict__ bbase, int* __restrict__ btot,
                                               const float* __restrict__ W1, uint* __restrict__ W1b,
                                               const float* __restrict__ W2, uint* __restrict__ W2b,
                                               const int* __restrict__ batch, int* gstart,
                                               float* __restrict__ pooled) {
    __shared__ int cur[NBUCK];
    __shared__ int tot[NBUCK];
    __shared__ int sc[256];
    int blk = blockIdx.x, t = threadIdx.x;
    if (blk >= NEB) {
        if (blk == NEB + 16) {
            for (int i = t; i < N_GRAPHS * DIM2; i += 256) pooled[i] = 0.f;
            return;
        }
        int g = (blk - NEB) * 256 + t;   // 0..4095
        {
            int s = g >> 9, tt = (g >> 6) & 7, q = (g >> 4) & 3, n = g & 15;
            int k0 = s * 32 + q * 8;
            int colw = tt * 16 + n;
            uint4 o;
            o.x = bf16pack(W1[(size_t)(k0 + 0) * DIM1 + colw], W1[(size_t)(k0 + 1) * DIM1 + colw]);
            o.y = bf16pack(W1[(size_t)(k0 + 2) * DIM1 + colw], W1[(size_t)(k0 + 3) * DIM1 + colw]);
            o.z = bf16pack(W1[(size_t)(k0 + 4) * DIM1 + colw], W1[(size_t)(k0 + 5) * DIM1 + colw]);
            o.w = bf16pack(W1[(size_t)(k0 + 6) * DIM1 + colw], W1[(size_t)(k0 + 7) * DIM1 + colw]);
            ((uint4*)W1b)[g] = o;
        }
        if (g < 512) {   // W2 B-fragments (rows permuted per featOf)
            int s = g >> 7, tt = (g >> 6) & 1, l = g & 63;
            int n = tt * 16 + (l & 15);
            int kb = s * 32 + (l >> 4) * 8;
            uint4 o;
            o.x = bf16pack(W2[(size_t)featOf(kb + 0) * DIM2 + n], W2[(size_t)featOf(kb + 1) * DIM2 + n]);
            o.y = bf16pack(W2[(size_t)featOf(kb + 2) * DIM2 + n], W2[(size_t)featOf(kb + 3) * DIM2 + n]);
            o.z = bf16pack(W2[(size_t)featOf(kb + 4) * DIM2 + n], W2[(size_t)featOf(kb + 5) * DIM2 + n]);
            o.w = bf16pack(W2[(size_t)featOf(kb + 6) * DIM2 + n], W2[(size_t)featOf(kb + 7) * DIM2 + n]);
            ((uint4*)W2b)[g] = o;
        }
        if (g <= N_GRAPHS) {
            int lo = 0, hi = N_NODES;
            while (lo < hi) { int mid = (lo + hi) >> 1; if (batch[mid] < g) lo = mid + 1; else hi = mid; }
            gstart[g] = lo;
        }
        return;
    }
    // ---- place path (blocks 0..97) ----
    int pre = 0, to = 0;
    for (int b2 = 0; b2 < NEB; ++b2) {
        int v = (t < NBUCK) ? hist[b2 * NBUCK + t] : 0;
        to += v;
        if (b2 < blk) pre += v;
    }
    if (t < NBUCK) tot[t] = to;
    sc[t] = (t < NBUCK) ? to : 0;
    __syncthreads();
    for (int off = 1; off < 256; off <<= 1) {
        int x = (t >= off) ? sc[t - off] : 0;
        __syncthreads();
        sc[t] += x;
        __syncthreads();
    }
    if (t < NBUCK) {
        int base = sc[t] - tot[t];          // exclusive bucket base
        cur[t] = base + pre;
        if (blk == 0) { bbase[t] = base; btot[t] = tot[t]; }
    }
    __syncthreads();
#pragma unroll
    for (int i = 0; i < 8; ++i) {
        int idx = blk * 2048 + i * 256 + t;
        if (idx < N_EDGES / 4) {
            int4 r4 = ((const int4*)row)[idx];
            int4 c4 = ((const int4*)col)[idx];
            int rs[4] = {r4.x, r4.y, r4.z, r4.w};
            int cs[4] = {c4.x, c4.y, c4.z, c4.w};
#pragma unroll
            for (int j = 0; j < 4; ++j) {
                int pos = atomicAdd(&cur[rs[j] >> 8], 1);
                bb[pos] = ((uint)(rs[j] & 255) << 16) | (uint)cs[j];
            }
        }
    }
}

// ---------------- build: per-bucket row sort -> dense ushort CSR + offs/cnt ----------------
__global__ __launch_bounds__(256) void k_build(const int* __restrict__ bbase, const int* __restrict__ btot,
                                               const uint* __restrict__ bb,
                                               int* __restrict__ offs, int* __restrict__ cnt,
                                               ushort* __restrict__ csr) {
    __shared__ int c256[256];
    __shared__ int cur256[256];
    __shared__ int wsum[4];
    int b = blockIdx.x, t = threadIdx.x;
    int start = bbase[b];
    int n = btot[b];
    c256[t] = 0;
    __syncthreads();
    for (int i = t; i < n; i += 256) atomicAdd(&c256[bb[start + i] >> 16], 1);
    __syncthreads();
    int w = t >> 6, l = t & 63;
    int v = c256[t];
    int incl = v;
#pragma unroll
    for (int off = 1; off < 64; off <<= 1) {
        int x = __shfl_up(incl, off, 64);
        if (l >= off) incl += x;
    }
    if (l == 63) wsum[w] = incl;
    __syncthreads();
    int woff = 0;
    for (int i = 0; i < w; ++i) woff += wsum[i];
    int excl = incl - v + woff;
    cur256[t] = excl;
    int r = b * 256 + t;
    if (r < N_NODES) { offs[r] = start + excl; cnt[r] = v; }
    __syncthreads();
    for (int i = t; i < n; i += 256) {
        uint e = bb[start + i];
        int pos = atomicAdd(&cur256[e >> 16], 1);
        csr[start + pos] = (ushort)(e & 0xFFFFu);
    }
}

// ---------------- GEMM1 (MFMA bf16): h1'[50000,128] = dinv * (X @ W1) ----------------
// h1u feature permutation: uint j = u*16+c holds features (32u+c, 32u+c+16).
#define G1_BM 128
#define AS_LD 20  // uints per row (16 data + 4 pad = 80 B)
__global__ __launch_bounds__(256) void k_gemm1(const float* __restrict__ X, const uint* __restrict__ W1b,
                                               const int* __restrict__ cnt, unsigned* __restrict__ h1u) {
    __shared__ uint w1s[16384];        // 64 KB: full W1 in B-frag order
    __shared__ uint As[G1_BM * AS_LD]; // 10 KB: A tile bf16, one K-step
    int t = threadIdx.x;
    int w = t >> 6, lane = t & 63, q = lane >> 4, m16 = lane & 15;
    int rowBase = blockIdx.x * G1_BM;

    {
        const uint4* src = (const uint4*)W1b;
        uint4* dst = (uint4*)w1s;
#pragma unroll
        for (int i = 0; i < 16; ++i) dst[i * 256 + t] = src[i * 256 + t];
    }

    f32x4 acc[2][8];
#pragma unroll
    for (int i = 0; i < 2; ++i)
#pragma unroll
        for (int j = 0; j < 8; ++j) acc[i][j] = (f32x4){0.f, 0.f, 0.f, 0.f};

    int ar = t >> 1, ah = t & 1;
    for (int s = 0; s < 8; ++s) {
        float4 f0 = {0,0,0,0}, f1 = {0,0,0,0}, f2 = {0,0,0,0}, f3 = {0,0,0,0};
        int grow = rowBase + ar;
        if (grow < N_NODES) {
            const float* src = X + (size_t)grow * DIM0 + s * 32 + ah * 16;
            f0 = *(const float4*)(src + 0);
            f1 = *(const float4*)(src + 4);
            f2 = *(const float4*)(src + 8);
            f3 = *(const float4*)(src + 12);
        }
        uint4 p0, p1;
        p0.x = bf16pack(f0.x, f0.y); p0.y = bf16pack(f0.z, f0.w);
        p0.z = bf16pack(f1.x, f1.y); p0.w = bf16pack(f1.z, f1.w);
        p1.x = bf16pack(f2.x, f2.y); p1.y = bf16pack(f2.z, f2.w);
        p1.z = bf16pack(f3.x, f3.y); p1.w = bf16pack(f3.z, f3.w);
        __syncthreads();
        *(uint4*)&As[ar * AS_LD + ah * 8 + 0] = p0;
        *(uint4*)&As[ar * AS_LD + ah * 8 + 4] = p1;
        __syncthreads();

        s16x8 af[2];
#pragma unroll
        for (int rt = 0; rt < 2; ++rt) {
            int arow = w * 32 + rt * 16 + m16;
            af[rt] = *(s16x8*)&As[arow * AS_LD + q * 4];
        }
#pragma unroll
        for (int tt = 0; tt < 8; ++tt) {
            s16x8 bf = *(s16x8*)&w1s[((s * 8 + tt) * 64 + lane) * 4];
            acc[0][tt] = __builtin_amdgcn_mfma_f32_16x16x32_bf16(af[0], bf, acc[0][tt], 0, 0, 0);
            acc[1][tt] = __builtin_amdgcn_mfma_f32_16x16x32_bf16(af[1], bf, acc[1][tt], 0, 0, 0);
        }
    }

#pragma unroll
    for (int rt = 0; rt < 2; ++rt) {
#pragma unroll
        for (int reg = 0; reg < 4; ++reg) {
            int row = rowBase + w * 32 + rt * 16 + q * 4 + reg;
            if (row < N_NODES) {
                float dv = rsqrtf((float)(cnt[row] + 1));
                unsigned* hr = h1u + (size_t)row * 64;
#pragma unroll
                for (int u = 0; u < 4; ++u)
                    hr[u * 16 + m16] = bf16pack(acc[rt][2 * u][reg] * dv, acc[rt][2 * u + 1][reg] * dv);
            }
        }
    }
}

// ---------------- agg1+gemm2 fused: block = 16 nodes ----------------
#define A1_LD 68   // uints per tile row (64 + 4 pad)
__global__ __launch_bounds__(256) void k_agg1g2(const unsigned* __restrict__ h1u, const int* __restrict__ cnt,
                                                const int* __restrict__ offs, const ushort* __restrict__ csr,
                                                const float* __restrict__ b1, const uint* __restrict__ W2b,
                                                unsigned* __restrict__ h2u) {
    __shared__ uint a1tile[16 * A1_LD];
    __shared__ float sdi[16];
    int t = threadIdx.x;
    int wv = t >> 6, lane = t & 63;
    int nb16 = blockIdx.x * 16;

#pragma unroll
    for (int i = 0; i < 4; ++i) {
        int m = wv * 4 + i;
        int node = nb16 + m;
        float2 acc = bf16x2(h1u[(size_t)node * 64 + lane]);  // self (already dinv-scaled)
        int n = cnt[node];
        const ushort* cp = csr + offs[node];
        int ec = 0;
        if (lane < n) ec = cp[lane];
        int j = 0;
        for (; j + 8 <= n; j += 8) {
            int c0 = __shfl(ec, j),     c1 = __shfl(ec, j + 1), c2 = __shfl(ec, j + 2), c3 = __shfl(ec, j + 3);
            int c4 = __shfl(ec, j + 4), c5 = __shfl(ec, j + 5), c6 = __shfl(ec, j + 6), c7 = __shfl(ec, j + 7);
            unsigned p0 = h1u[(size_t)c0 * 64 + lane];
            unsigned p1 = h1u[(size_t)c1 * 64 + lane];
            unsigned p2 = h1u[(size_t)c2 * 64 + lane];
            unsigned p3 = h1u[(size_t)c3 * 64 + lane];
            unsigned p4 = h1u[(size_t)c4 * 64 + lane];
            unsigned p5 = h1u[(size_t)c5 * 64 + lane];
            unsigned p6 = h1u[(size_t)c6 * 64 + lane];
            unsigned p7 = h1u[(size_t)c7 * 64 + lane];
            float2 v0 = bf16x2(p0), v1 = bf16x2(p1), v2 = bf16x2(p2), v3 = bf16x2(p3);
            float2 v4 = bf16x2(p4), v5 = bf16x2(p5), v6 = bf16x2(p6), v7 = bf16x2(p7);
            acc.x += (v0.x + v1.x) + (v2.x + v3.x) + (v4.x + v5.x) + (v6.x + v7.x);
            acc.y += (v0.y + v1.y) + (v2.y + v3.y) + (v4.y + v5.y) + (v6.y + v7.y);
        }
        for (; j + 4 <= n; j += 4) {
            int c0 = __shfl(ec, j), c1 = __shfl(ec, j + 1), c2 = __shfl(ec, j + 2), c3 = __shfl(ec, j + 3);
            unsigned p0 = h1u[(size_t)c0 * 64 + lane];
            unsigned p1 = h1u[(size_t)c1 * 64 + lane];
            unsigned p2 = h1u[(size_t)c2 * 64 + lane];
            unsigned p3 = h1u[(size_t)c3 * 64 + lane];
            float2 v0 = bf16x2(p0), v1 = bf16x2(p1), v2 = bf16x2(p2), v3 = bf16x2(p3);
            acc.x += (v0.x + v1.x) + (v2.x + v3.x);
            acc.y += (v0.y + v1.y) + (v2.y + v3.y);
        }
        for (; j < n; ++j) {
            int c = __shfl(ec, j);
            float2 v = bf16x2(h1u[(size_t)c * 64 + lane]);
            acc.x += v.x; acc.y += v.y;
        }
        float di = rsqrtf((float)(n + 1));
        if (lane == 0) sdi[m] = di;
        int f0 = (lane >> 4) * 32 + (lane & 15);
        acc.x = fmaxf(acc.x * di + b1[f0], 0.f);
        acc.y = fmaxf(acc.y * di + b1[f0 + 16], 0.f);
        a1tile[m * A1_LD + lane] = bf16pack(acc.x, acc.y);
    }
    __syncthreads();

    if (wv == 0) {
        int q = lane >> 4, m16 = lane & 15;
        f32x4 accA = (f32x4){0.f, 0.f, 0.f, 0.f};
        f32x4 accB = (f32x4){0.f, 0.f, 0.f, 0.f};
#pragma unroll
        for (int s = 0; s < 4; ++s) {
            s16x8 af = *(s16x8*)&a1tile[m16 * A1_LD + s * 16 + q * 4];
            s16x8 bf0 = *(const s16x8*)(W2b + (size_t)((s * 2 + 0) * 64 + lane) * 4);
            s16x8 bf1 = *(const s16x8*)(W2b + (size_t)((s * 2 + 1) * 64 + lane) * 4);
            accA = __builtin_amdgcn_mfma_f32_16x16x32_bf16(af, bf0, accA, 0, 0, 0);
            accB = __builtin_amdgcn_mfma_f32_16x16x32_bf16(af, bf1, accB, 0, 0, 0);
        }
#pragma unroll
        for (int r = 0; r < 4; ++r) {
            int node = nb16 + q * 4 + r;
            float dv = sdi[q * 4 + r];
            // h2u position m16 holds output features (m16, m16+16)
            h2u[(size_t)node * 16 + m16] = bf16pack(accA[r] * dv, accB[r] * dv);
        }
    }
}

// ---------------- agg2 + per-graph partial pool: block = 16 nodes ----------------
__global__ __launch_bounds__(256) void k_agg2pool(const unsigned* __restrict__ h2u, const int* __restrict__ cnt,
                                                  const int* __restrict__ offs, const ushort* __restrict__ csr,
                                                  const int* __restrict__ batch, float* __restrict__ pooled) {
    __shared__ float2 red[16][16];
    int t = threadIdx.x;
    int nb16 = blockIdx.x * 16;
    int node = nb16 + (t >> 4);
    int l = t & 15;
    float2 acc = bf16x2(h2u[(size_t)node * 16 + l]);  // self term
    int n = cnt[node];
    const ushort* cp = csr + offs[node];
    for (int base = 0; base < n; base += 16) {
        int m = min(16, n - base);
        int ec = 0;
        if (l < m) ec = cp[base + l];
        int j = 0;
        for (; j + 4 <= m; j += 4) {
            int c0 = __shfl(ec, j, 16), c1 = __shfl(ec, j + 1, 16);
            int c2 = __shfl(ec, j + 2, 16), c3 = __shfl(ec, j + 3, 16);
            unsigned p0 = h2u[(size_t)c0 * 16 + l];
            unsigned p1 = h2u[(size_t)c1 * 16 + l];
            unsigned p2 = h2u[(size_t)c2 * 16 + l];
            unsigned p3 = h2u[(size_t)c3 * 16 + l];
            float2 v0 = bf16x2(p0), v1 = bf16x2(p1), v2 = bf16x2(p2), v3 = bf16x2(p3);
            acc.x += v0.x + v1.x + v2.x + v3.x;
            acc.y += v0.y + v1.y + v2.y + v3.y;
        }
        for (; j < m; ++j) {
            int c = __shfl(ec, j, 16);
            float2 v = bf16x2(h2u[(size_t)c * 16 + l]);
            acc.x += v.x; acc.y += v.y;
        }
    }
    float di = rsqrtf((float)(n + 1));
    red[t >> 4][l] = make_float2(acc.x * di, acc.y * di);
    __syncthreads();
    if (t < 16) {
        float2 run = make_float2(0.f, 0.f);
        int gprev = batch[nb16];
        for (int m = 0; m < 16; ++m) {
            int g = batch[nb16 + m];
            if (g != gprev) {
                atomicAdd(&pooled[gprev * DIM2 + t], run.x);
                atomicAdd(&pooled[gprev * DIM2 + t + 16], run.y);
                run = make_float2(0.f, 0.f);
                gprev = g;
            }
            float2 v = red[m][t];
            run.x += v.x; run.y += v.y;
        }
        atomicAdd(&pooled[gprev * DIM2 + t], run.x);
        atomicAdd(&pooled[gprev * DIM2 + t + 16], run.y);
    }
}

// ---------------- final: mean + bias + log_softmax (1 wave / graph) ----------------
__global__ __launch_bounds__(64) void k_final(const float* __restrict__ pooled, const int* __restrict__ gstart,
                                              const float* __restrict__ b2, float* __restrict__ out) {
    int g = blockIdx.x;
    int lane = threadIdx.x;
    float cntf = fmaxf((float)(gstart[g + 1] - gstart[g]), 1.0f);
    float val = 0.f, v = -INFINITY;
    if (lane < DIM2) {
        val = pooled[g * DIM2 + lane] / cntf + b2[lane];
        v = val;
    }
#pragma unroll
    for (int m = 16; m >= 1; m >>= 1) v = fmaxf(v, __shfl_xor(v, m, 32));
    float ex = (lane < DIM2) ? expf(val - v) : 0.f;
#pragma unroll
    for (int m = 16; m >= 1; m >>= 1) ex += __shfl_xor(ex, m, 32);
    if (lane < DIM2) out[g * DIM2 + lane] = val - v - logf(ex);
}

extern "C" void kernel_launch(void* const* d_in, const int* in_sizes, int n_in,
                              void* d_out, int out_size, void* d_ws, size_t ws_size,
                              hipStream_t stream) {
    const float* x     = (const float*)d_in[0];
    const int*   eidx  = (const int*)d_in[1];
    const int*   batch = (const int*)d_in[2];
    const float* W1    = (const float*)d_in[3];
    const float* b1    = (const float*)d_in[4];
    const float* W2    = (const float*)d_in[5];
    const float* b2    = (const float*)d_in[6];
    const int* row = eidx;
    const int* col = eidx + N_EDGES;
    float* out = (float*)d_out;

    // workspace layout (16B aligned chunks)
    char* p = (char*)d_ws;
    int*    cnt    = (int*)p;    p += (size_t)N_NODES * 4;
    int*    offs   = (int*)p;    p += (size_t)N_NODES * 4 + 16;
    int*    gstart = (int*)p;    p += 768;          // 129 ints, padded
    uint*   W1b    = (uint*)p;   p += 4096 * 16;    // 64 KB swizzled bf16 W1
    uint*   W2b    = (uint*)p;   p += 512 * 16;     // 8 KB W2 B-fragments
    int*    hist   = (int*)p;    p += (size_t)NEB * NBUCK * 4 + 32;  // 77 KB, block-major
    int*    bbase  = (int*)p;    p += 1024;
    int*    btot   = (int*)p;    p += 1024;
    float*  pooled = (float*)p;  p += (size_t)N_GRAPHS * DIM2 * 4;   // 16 KB
    uint*   bb     = (uint*)p;   p += (size_t)N_EDGES * 4;           // 3.2 MB staging
    ushort* csr    = (ushort*)p; p += (size_t)N_EDGES * 2;           // 1.6 MB dense CSR
    unsigned* h1u  = (unsigned*)p; p += (size_t)N_NODES * 64 * 4;    // 12.8 MB
    unsigned* h2u  = (unsigned*)p; p += (size_t)N_NODES * 16 * 4;    // 3.2 MB

    k_hist<<<NEB, 256, 0, stream>>>(row, hist);
    k_place<<<NEB + 17, 256, 0, stream>>>(row, col, hist, bb, bbase, btot,
                                          W1, W1b, W2, W2b, batch, gstart, pooled);
    k_build<<<NBUCK, 256, 0, stream>>>(bbase, btot, bb, offs, cnt, csr);

    k_gemm1<<<(N_NODES + G1_BM - 1) / G1_BM, 256, 0, stream>>>(x, W1b, cnt, h1u);
    k_agg1g2<<<N_NODES / 16, 256, 0, stream>>>(h1u, cnt, offs, csr, b1, W2b, h2u);
    k_agg2pool<<<N_NODES / 16, 256, 0, stream>>>(h2u, cnt, offs, csr, batch, pooled);
    k_final<<<N_GRAPHS, 64, 0, stream>>>(pooled, gstart, b2, out);
}